// Round 22
// baseline (172.218 us; speedup 1.0000x reference)
//
#include <hip/hip_runtime.h>
#include <stdint.h>

typedef unsigned short u16;
typedef __attribute__((ext_vector_type(4))) float f32x4;
typedef __attribute__((ext_vector_type(4))) uint32_t u32x4;
typedef __attribute__((ext_vector_type(8))) __bf16 bf16x8;

#define B_ 4
#define H_ 8
#define T_ 2048
#define C_ 256
#define KC 2048  /* concatenated K = H*C */
#define NCH 32   /* 64-row G chunks per b */
#define XP 528   /* 256-col bf16 LDS pitch (bytes) */
#define SP 144   /* 64-col bf16 LDS pitch (bytes) */

static __device__ __forceinline__ f32x4 mfma16(u32x4 a, u32x4 b, f32x4 c) {
  union { u32x4 u; bf16x8 b; } A, Bb;
  A.u = a; Bb.u = b;
  return __builtin_amdgcn_mfma_f32_16x16x32_bf16(A.b, Bb.b, c, 0, 0, 0);
}
static __device__ __forceinline__ u16 f2b(float f) {
  union { __bf16 h; u16 u; } r; r.h = (__bf16)f; return r.u;
}

// ---- k_prep: rp->bf16 + rp^T + Q^T + E->EC permute, one launch ----
__global__ __launch_bounds__(256) void k_prep(const float* __restrict__ rp_f,
                                              const float* __restrict__ E_f,
                                              const float* __restrict__ Q_f,
                                              u16* __restrict__ rbf,
                                              u16* __restrict__ rpT,
                                              u16* __restrict__ qtb,
                                              u16* __restrict__ ec) {
  __shared__ u16 l[64][72];
  const int r = blockIdx.x, tid = threadIdx.x;
  if (r < 512) {
    const int b = r >> 7, i0 = ((r >> 5) & 3) * 64, t0 = (r & 31) * 64;
    const int tj = tid & 63, tq = tid >> 6;
    const float* src = rp_f + (size_t)b * T_ * C_;
    u16* rb = rbf + (size_t)b * T_ * C_;
    #pragma unroll
    for (int rr = 0; rr < 16; ++rr) {
      int tl = rr * 4 + tq;
      u16 v = f2b(src[(size_t)(t0 + tl) * C_ + i0 + tj]);
      l[tl][tj] = v;
      rb[(size_t)(t0 + tl) * C_ + i0 + tj] = v;
    }
    __syncthreads();
    u16* dst = rpT + (size_t)b * C_ * T_;
    #pragma unroll
    for (int rr = 0; rr < 16; ++rr) {
      int il = rr * 4 + tq;
      dst[(size_t)(i0 + il) * T_ + t0 + tj] = l[tj][il];
    }
  } else if (r < 640) {
    const int q = r - 512;
    const int h = q >> 4, i0 = ((q >> 2) & 3) * 64, j0 = (q & 3) * 64;
    const int tj = tid & 63, tq = tid >> 6;
    const float* qh = Q_f + (size_t)h * C_ * C_;
    #pragma unroll
    for (int rr = 0; rr < 16; ++rr) {
      int i = rr * 4 + tq;
      l[i][tj] = f2b(qh[(size_t)(i0 + i) * C_ + j0 + tj]);
    }
    __syncthreads();
    u16* qth = qtb + (size_t)h * C_ * C_;
    #pragma unroll
    for (int rr = 0; rr < 16; ++rr) {
      int j = rr * 4 + tq;
      qth[(size_t)(j0 + j) * C_ + i0 + tj] = l[tj][j];
    }
  } else {  // E[h][i][j] -> EC[i][h*256+j] (bf16)
    const int q = r - 640;
    size_t e = ((size_t)q * 256 + tid) * 4;
    int h = (int)(e >> 16), i = (int)((e >> 8) & 255), j = (int)(e & 255);
    f32x4 v = *(const f32x4*)(E_f + e);
    union { u16 h4[4]; uint64_t qq; } p;
    #pragma unroll
    for (int c = 0; c < 4; ++c) p.h4[c] = f2b(v[c]);
    *(uint64_t*)(ec + (size_t)i * KC + h * 256 + j) = p.qq;
  }
}

// ---- k_gram: G_excl[b][k][i][j] = sum_{u<64k} rp[u][i]*rp[u][j], bf16 ----
__global__ __launch_bounds__(256) void k_gram(const u16* __restrict__ rpT,
                                              u16* __restrict__ G) {
  __shared__ u16 gls[4][16][20];
  const int js = blockIdx.x, iq = blockIdx.y, b = blockIdx.z;
  const int tid = threadIdx.x, lane = tid & 63, v = tid >> 6;
  const int l15 = lane & 15, lq = lane >> 4;
  const u16* rtb = rpT + (size_t)b * C_ * T_;
  const int irow = 64 * iq + 16 * v;
  const int rrow = lane >> 2, rc4 = (lane & 3) * 4;

  f32x4 acc = (f32x4)0.f;

  for (int k = 0; k < NCH; ++k) {
    #pragma unroll
    for (int rr = 0; rr < 4; ++rr)
      gls[v][4 * lq + rr][l15] = f2b(acc[rr]);
    __builtin_amdgcn_wave_barrier();
    u16* gk = G + (size_t)(b * NCH + k) * C_ * C_;
    *(uint64_t*)(gk + (size_t)(irow + rrow) * C_ + 16 * js + rc4) =
        *(const uint64_t*)&gls[v][rrow][rc4];
    __builtin_amdgcn_wave_barrier();

    u32x4 am[2], bn[2];
    #pragma unroll
    for (int kk = 0; kk < 2; ++kk) {
      am[kk] = *(const u32x4*)(rtb + (size_t)(irow + l15) * T_ +
                               64 * k + 32 * kk + 8 * lq);
      bn[kk] = *(const u32x4*)(rtb + (size_t)(16 * js + l15) * T_ +
                               64 * k + 32 * kk + 8 * lq);
    }
    #pragma unroll
    for (int kk = 0; kk < 2; ++kk)
      acc = mfma16(am[kk], bn[kk], acc);
  }
}

// ---- k_z: dual-head single pass; 512 threads; shared G/rp operands ----
// (r21 proven body, unchanged: 63 us, VGPR 128, no spills)
__global__ __launch_bounds__(512, 2) void k_z(const u16* __restrict__ rbf,
                                              const u16* __restrict__ rpT,
                                              const u16* __restrict__ qtb,
                                              const u16* __restrict__ G,
                                              u16* __restrict__ ZC) {
  __shared__ __align__(16) char smem[119808];
  char* rp_l = smem;                 // [64][528]
  char* x0   = smem + 33792;         // QR/Z head0
  char* x1   = smem + 67584;         // QR/Z head1
  char* s0   = smem + 101376;        // S head0 [64][144]
  char* s1   = smem + 110592;        // S head1

  const int tile = blockIdx.x, b = blockIdx.y, hg = blockIdx.z;
  const int t0 = tile * 64;
  const int tid = threadIdx.x, lane = tid & 63, w = tid >> 6;
  const int l15 = lane & 15, lq = lane >> 4;
  const int mh = w >> 2, nq = w & 3;

  const u16* rpb = rbf + (size_t)b * T_ * C_;
  const u16* rtb = rpT + (size_t)b * C_ * T_;
  const u16* gt  = G + (size_t)(b * NCH + tile) * C_ * C_;
  const u16* qth0 = qtb + (size_t)(2 * hg) * C_ * C_;
  const u16* qth1 = qtb + (size_t)(2 * hg + 1) * C_ * C_;

  // ---- stage rp diagonal tile ----
  {
    const int row = tid >> 3, seg = tid & 7;
    const char* src = (const char*)(rpb + (size_t)(t0 + row) * C_);
    #pragma unroll
    for (int c = 0; c < 4; ++c) {
      u32x4 vv = *(const u32x4*)(src + seg * 64 + c * 16);
      *(u32x4*)(rp_l + (size_t)row * XP + seg * 64 + c * 16) = vv;
    }
  }
  __syncthreads();

  // ---- QR both heads: wave w owns n-tiles {2w, 2w+1}, all 4 m-tiles ----
  #pragma unroll
  for (int nn = 0; nn < 2; ++nn) {
    const int nt = 2 * w + nn;
    u32x4 bq0[8], bq1[8];
    #pragma unroll
    for (int kk = 0; kk < 8; ++kk) {
      bq0[kk] = *(const u32x4*)(qth0 + (size_t)(16 * nt + l15) * C_ +
                                32 * kk + 8 * lq);
      bq1[kk] = *(const u32x4*)(qth1 + (size_t)(16 * nt + l15) * C_ +
                                32 * kk + 8 * lq);
    }
    #pragma unroll
    for (int mm = 0; mm < 4; ++mm) {
      u32x4 am[8];
      #pragma unroll
      for (int kk = 0; kk < 8; ++kk)
        am[kk] = *(const u32x4*)(rp_l + (size_t)(16 * mm + l15) * XP +
                                 64 * kk + 16 * lq);
      f32x4 q0 = (f32x4)0.f, q1 = (f32x4)0.f;
      #pragma unroll
      for (int kk = 0; kk < 8; ++kk) {
        q0 = mfma16(am[kk], bq0[kk], q0);
        q1 = mfma16(am[kk], bq1[kk], q1);
      }
      #pragma unroll
      for (int rr = 0; rr < 4; ++rr) {
        size_t off = (size_t)(16 * mm + 4 * lq + rr) * XP + (16 * nt + l15) * 2;
        *(u16*)(x0 + off) = f2b(q0[rr]);
        *(u16*)(x1 + off) = f2b(q1[rr]);
      }
    }
  }
  __syncthreads();

  // ---- Z_full: wave w -> rows 32mh..+32, cols 64nq..+64; bg shared ----
  f32x4 a0[2][4], a1[2][4];
  #pragma unroll
  for (int m = 0; m < 2; ++m)
    #pragma unroll
    for (int n = 0; n < 4; ++n) { a0[m][n] = (f32x4)0.f; a1[m][n] = (f32x4)0.f; }

  #pragma unroll
  for (int n = 0; n < 4; ++n) {
    const int nt = 4 * nq + n;
    u32x4 bg[8];
    #pragma unroll
    for (int kk = 0; kk < 8; ++kk)
      bg[kk] = *(const u32x4*)(gt + (size_t)(16 * nt + l15) * C_ +
                               32 * kk + 8 * lq);
    #pragma unroll
    for (int m = 0; m < 2; ++m) {
      const size_t roff = (size_t)(16 * (2 * mh + m) + l15) * XP;
      u32x4 qa0[8], qa1[8];
      #pragma unroll
      for (int kk = 0; kk < 8; ++kk) {
        qa0[kk] = *(const u32x4*)(x0 + roff + 64 * kk + 16 * lq);
        qa1[kk] = *(const u32x4*)(x1 + roff + 64 * kk + 16 * lq);
      }
      #pragma unroll
      for (int kk = 0; kk < 8; ++kk) {
        a0[m][n] = mfma16(qa0[kk], bg[kk], a0[m][n]);
        a1[m][n] = mfma16(qa1[kk], bg[kk], a1[m][n]);
      }
    }
  }

  // ---- S: waves 0-3 head0 / 4-7 head1; wave does m-tile (w&3), 4 u-tiles ----
  {
    const int ms = w & 3;
    const char* xs = (w >> 2) ? x1 : x0;
    char* ss = (w >> 2) ? s1 : s0;
    u32x4 qa3[8];
    #pragma unroll
    for (int kk = 0; kk < 8; ++kk)
      qa3[kk] = *(const u32x4*)(xs + (size_t)(16 * ms + l15) * XP +
                                64 * kk + 16 * lq);
    #pragma unroll
    for (int un = 0; un < 4; ++un) {
      u32x4 bs[8];
      #pragma unroll
      for (int kk = 0; kk < 8; ++kk)
        bs[kk] = *(const u32x4*)(rp_l + (size_t)(16 * un + l15) * XP +
                                 64 * kk + 16 * lq);
      f32x4 sacc = (f32x4)0.f;
      #pragma unroll
      for (int kk = 0; kk < 8; ++kk) sacc = mfma16(qa3[kk], bs[kk], sacc);
      #pragma unroll
      for (int rr = 0; rr < 4; ++rr) {
        int tl = 16 * ms + 4 * lq + rr;
        int ul = 16 * un + l15;
        float sv = (ul > tl) ? 0.f : sacc[rr];
        *(u16*)(ss + (size_t)tl * SP + ul * 2) = f2b(sv);
      }
    }
  }
  __syncthreads();  // all x/rp_l reads done; s0/s1 visible

  // ---- Z_loc both heads: vb shared ----
  {
    u32x4 sa0[2][2], sa1[2][2];
    #pragma unroll
    for (int m = 0; m < 2; ++m)
      #pragma unroll
      for (int kk = 0; kk < 2; ++kk) {
        size_t off = (size_t)(16 * (2 * mh + m) + l15) * SP + 64 * kk + 16 * lq;
        sa0[m][kk] = *(const u32x4*)(s0 + off);
        sa1[m][kk] = *(const u32x4*)(s1 + off);
      }
    #pragma unroll
    for (int n = 0; n < 4; ++n) {
      const int nt = 4 * nq + n;
      #pragma unroll
      for (int kk = 0; kk < 2; ++kk) {
        u32x4 vb = *(const u32x4*)(rtb + (size_t)(16 * nt + l15) * T_ +
                                   t0 + 32 * kk + 8 * lq);
        #pragma unroll
        for (int m = 0; m < 2; ++m) {
          a0[m][n] = mfma16(sa0[m][kk], vb, a0[m][n]);
          a1[m][n] = mfma16(sa1[m][kk], vb, a1[m][n]);
        }
      }
    }
  }

  // ---- Z (bf16) -> x0/x1 (disjoint per wave) ----
  #pragma unroll
  for (int m = 0; m < 2; ++m)
    #pragma unroll
    for (int n = 0; n < 4; ++n)
      #pragma unroll
      for (int rr = 0; rr < 4; ++rr) {
        size_t off = (size_t)(16 * (2 * mh + m) + 4 * lq + rr) * XP +
                     (16 * (4 * nq + n) + l15) * 2;
        *(u16*)(x0 + off) = f2b(a0[m][n][rr]);
        *(u16*)(x1 + off) = f2b(a1[m][n][rr]);
      }
  __syncthreads();

  // ---- coalesced ZC stores, both heads ----
  {
    const int row = tid >> 3, seg = tid & 7;
    char* d0 = (char*)(ZC + ((size_t)(b * T_ + t0 + row) * KC + (2 * hg) * 256));
    char* d1 = (char*)(ZC + ((size_t)(b * T_ + t0 + row) * KC + (2 * hg + 1) * 256));
    #pragma unroll
    for (int c = 0; c < 4; ++c) {
      u32x4 v0 = *(const u32x4*)(x0 + (size_t)row * XP + seg * 64 + c * 16);
      u32x4 v1 = *(const u32x4*)(x1 + (size_t)row * XP + seg * 64 + c * 16);
      *(u32x4*)(d0 + seg * 64 + c * 16) = v0;
      *(u32x4*)(d1 + seg * 64 + c * 16) = v1;
    }
  }
}

// ---- k_o v2: flat GEMM O[b] = ZC[b] * EC^T, 4 blocks/CU ----
// grid (128 M-tiles of 16, 2 N-halves of 128, 4 b) = 1024 blocks, 256 thr.
// Per-wave: 16 rows x 32 cols, acc[2] = 8 AGPR; ZC L3-resident (read 2x).
__global__ __launch_bounds__(256) void k_o(const u16* __restrict__ ZC,
                                           const u16* __restrict__ ec,
                                           float* __restrict__ out) {
  const int mt = blockIdx.x, nh = blockIdx.y, b = blockIdx.z;
  const int tid = threadIdx.x, lane = tid & 63, v = tid >> 6;
  const int l15 = lane & 15, lq = lane >> 4;

  const u16* za_b = ZC + (size_t)(b * T_ + mt * 16) * KC;
  const u16* eb_b = ec + (size_t)(nh * 128 + 32 * v) * KC;

  f32x4 acc[2];
  acc[0] = (f32x4)0.f;
  acc[1] = (f32x4)0.f;

  #pragma unroll 4
  for (int kk = 0; kk < 64; ++kk) {
    u32x4 am, bn[2];
    am = *(const u32x4*)(za_b + (size_t)l15 * KC + 32 * kk + 8 * lq);
    #pragma unroll
    for (int n = 0; n < 2; ++n)
      bn[n] = *(const u32x4*)(eb_b + (size_t)(16 * n + l15) * KC +
                              32 * kk + 8 * lq);
    #pragma unroll
    for (int n = 0; n < 2; ++n)
      acc[n] = mfma16(am, bn[n], acc[n]);
  }

  float* ob = out + ((size_t)b * T_ + mt * 16) * C_ + nh * 128 + 32 * v;
  #pragma unroll
  for (int n = 0; n < 2; ++n)
    #pragma unroll
    for (int rr = 0; rr < 4; ++rr)
      ob[(size_t)(4 * lq + rr) * C_ + 16 * n + l15] = acc[n][rr];
}

extern "C" void kernel_launch(void* const* d_in, const int* in_sizes, int n_in,
                              void* d_out, int out_size, void* d_ws, size_t ws_size,
                              hipStream_t stream) {
  (void)ws_size; (void)out_size;
  const float* rp_f = nullptr;
  const float* sm[2] = {nullptr, nullptr};
  int ns = 0;
  for (int i = 0; i < n_in; ++i) {
    if (in_sizes[i] == 2097152) {
      rp_f = (const float*)d_in[i];
    } else if (ns < 2) {
      sm[ns++] = (const float*)d_in[i];
    }
  }
  const float* E_f = sm[0];
  const float* Q_f = sm[1];

  // ws (58 MB): G [0,16M) | rbf [16,20M) | rpT [20,24M) | Qt [24,25M)
  //             | EC [25,26M) | ZC bf16 [26,58M)
  const size_t MB = 1024 * 1024;
  u16* G   = (u16*)d_ws;
  u16* rbf = (u16*)((char*)d_ws + 16 * MB);
  u16* rpT = (u16*)((char*)d_ws + 20 * MB);
  u16* qtb = (u16*)((char*)d_ws + 24 * MB);
  u16* ec  = (u16*)((char*)d_ws + 25 * MB);
  u16* ZC  = (u16*)((char*)d_ws + 26 * MB);
  float* outf = (float*)d_out;

  k_prep<<<1152, 256, 0, stream>>>(rp_f, E_f, Q_f, rbf, rpT, qtb, ec);
  k_gram<<<dim3(16, 4, 4), 256, 0, stream>>>(rpT, G);
  k_z<<<dim3(32, 4, 4), 512, 0, stream>>>(rbf, rpT, qtb, G, ZC);
  k_o<<<dim3(128, 2, 4), 256, 0, stream>>>(ZC, ec, outf);
}

// Round 23
// 120.172 us; speedup vs baseline: 1.4331x; 1.4331x over previous
//
#include <hip/hip_runtime.h>
#include <stdint.h>

typedef unsigned short u16;
typedef __attribute__((ext_vector_type(4))) float f32x4;
typedef __attribute__((ext_vector_type(4))) uint32_t u32x4;
typedef __attribute__((ext_vector_type(8))) __bf16 bf16x8;

#define B_ 4
#define H_ 8
#define T_ 2048
#define C_ 256
#define KC 2048  /* concatenated K = H*C (EC row length) */
#define NCH 32   /* 64-row G chunks per b */
#define XP 528   /* 256-col bf16 LDS pitch (bytes) */
#define SP 144   /* 64-col bf16 LDS pitch (bytes) */

static __device__ __forceinline__ f32x4 mfma16(u32x4 a, u32x4 b, f32x4 c) {
  union { u32x4 u; bf16x8 b; } A, Bb;
  A.u = a; Bb.u = b;
  return __builtin_amdgcn_mfma_f32_16x16x32_bf16(A.b, Bb.b, c, 0, 0, 0);
}
static __device__ __forceinline__ u16 f2b(float f) {
  union { __bf16 h; u16 u; } r; r.h = (__bf16)f; return r.u;
}

// ---- k_prep: rp->bf16 + rp^T + Q^T + E->EC permute, one launch ----
__global__ __launch_bounds__(256) void k_prep(const float* __restrict__ rp_f,
                                              const float* __restrict__ E_f,
                                              const float* __restrict__ Q_f,
                                              u16* __restrict__ rbf,
                                              u16* __restrict__ rpT,
                                              u16* __restrict__ qtb,
                                              u16* __restrict__ ec) {
  __shared__ u16 l[64][72];
  const int r = blockIdx.x, tid = threadIdx.x;
  if (r < 512) {
    const int b = r >> 7, i0 = ((r >> 5) & 3) * 64, t0 = (r & 31) * 64;
    const int tj = tid & 63, tq = tid >> 6;
    const float* src = rp_f + (size_t)b * T_ * C_;
    u16* rb = rbf + (size_t)b * T_ * C_;
    #pragma unroll
    for (int rr = 0; rr < 16; ++rr) {
      int tl = rr * 4 + tq;
      u16 v = f2b(src[(size_t)(t0 + tl) * C_ + i0 + tj]);
      l[tl][tj] = v;
      rb[(size_t)(t0 + tl) * C_ + i0 + tj] = v;
    }
    __syncthreads();
    u16* dst = rpT + (size_t)b * C_ * T_;
    #pragma unroll
    for (int rr = 0; rr < 16; ++rr) {
      int il = rr * 4 + tq;
      dst[(size_t)(i0 + il) * T_ + t0 + tj] = l[tj][il];
    }
  } else if (r < 640) {
    const int q = r - 512;
    const int h = q >> 4, i0 = ((q >> 2) & 3) * 64, j0 = (q & 3) * 64;
    const int tj = tid & 63, tq = tid >> 6;
    const float* qh = Q_f + (size_t)h * C_ * C_;
    #pragma unroll
    for (int rr = 0; rr < 16; ++rr) {
      int i = rr * 4 + tq;
      l[i][tj] = f2b(qh[(size_t)(i0 + i) * C_ + j0 + tj]);
    }
    __syncthreads();
    u16* qth = qtb + (size_t)h * C_ * C_;
    #pragma unroll
    for (int rr = 0; rr < 16; ++rr) {
      int j = rr * 4 + tq;
      qth[(size_t)(j0 + j) * C_ + i0 + tj] = l[tj][j];
    }
  } else {  // E[h][i][j] -> EC[i][h*256+j] (bf16)
    const int q = r - 640;
    size_t e = ((size_t)q * 256 + tid) * 4;
    int h = (int)(e >> 16), i = (int)((e >> 8) & 255), j = (int)(e & 255);
    f32x4 v = *(const f32x4*)(E_f + e);
    union { u16 h4[4]; uint64_t qq; } p;
    #pragma unroll
    for (int c = 0; c < 4; ++c) p.h4[c] = f2b(v[c]);
    *(uint64_t*)(ec + (size_t)i * KC + h * 256 + j) = p.qq;
  }
}

// ---- k_gram: G_excl[b][k][i][j] = sum_{u<64k} rp[u][i]*rp[u][j], bf16 ----
__global__ __launch_bounds__(256) void k_gram(const u16* __restrict__ rpT,
                                              u16* __restrict__ G) {
  __shared__ u16 gls[4][16][20];
  const int js = blockIdx.x, iq = blockIdx.y, b = blockIdx.z;
  const int tid = threadIdx.x, lane = tid & 63, v = tid >> 6;
  const int l15 = lane & 15, lq = lane >> 4;
  const u16* rtb = rpT + (size_t)b * C_ * T_;
  const int irow = 64 * iq + 16 * v;
  const int rrow = lane >> 2, rc4 = (lane & 3) * 4;

  f32x4 acc = (f32x4)0.f;

  for (int k = 0; k < NCH; ++k) {
    #pragma unroll
    for (int rr = 0; rr < 4; ++rr)
      gls[v][4 * lq + rr][l15] = f2b(acc[rr]);
    __builtin_amdgcn_wave_barrier();
    u16* gk = G + (size_t)(b * NCH + k) * C_ * C_;
    *(uint64_t*)(gk + (size_t)(irow + rrow) * C_ + 16 * js + rc4) =
        *(const uint64_t*)&gls[v][rrow][rc4];
    __builtin_amdgcn_wave_barrier();

    u32x4 am[2], bn[2];
    #pragma unroll
    for (int kk = 0; kk < 2; ++kk) {
      am[kk] = *(const u32x4*)(rtb + (size_t)(irow + l15) * T_ +
                               64 * k + 32 * kk + 8 * lq);
      bn[kk] = *(const u32x4*)(rtb + (size_t)(16 * js + l15) * T_ +
                               64 * k + 32 * kk + 8 * lq);
    }
    #pragma unroll
    for (int kk = 0; kk < 2; ++kk)
      acc = mfma16(am[kk], bn[kk], acc);
  }
}

// ---- k_z: dual-head pass + fused epilogue; partial-O stores (no atomics) ----
// part[hg][b][t][i] = Z_h0*E_h0^T + Z_h1*E_h1^T for h = {2hg, 2hg+1}.
__global__ __launch_bounds__(512, 2) void k_z(const u16* __restrict__ rbf,
                                              const u16* __restrict__ rpT,
                                              const u16* __restrict__ qtb,
                                              const u16* __restrict__ G,
                                              const u16* __restrict__ ec,
                                              float* __restrict__ part) {
  __shared__ __align__(16) char smem[119808];
  char* rp_l = smem;                 // [64][528]
  char* x0   = smem + 33792;         // QR/Z head0
  char* x1   = smem + 67584;         // QR/Z head1
  char* s0   = smem + 101376;        // S head0 [64][144]
  char* s1   = smem + 110592;        // S head1

  const int tile = blockIdx.x, b = blockIdx.y, hg = blockIdx.z;
  const int t0 = tile * 64;
  const int tid = threadIdx.x, lane = tid & 63, w = tid >> 6;
  const int l15 = lane & 15, lq = lane >> 4;
  const int mh = w >> 2, nq = w & 3;

  const u16* rpb = rbf + (size_t)b * T_ * C_;
  const u16* rtb = rpT + (size_t)b * C_ * T_;
  const u16* gt  = G + (size_t)(b * NCH + tile) * C_ * C_;
  const u16* qth0 = qtb + (size_t)(2 * hg) * C_ * C_;
  const u16* qth1 = qtb + (size_t)(2 * hg + 1) * C_ * C_;

  // ---- stage rp diagonal tile ----
  {
    const int row = tid >> 3, seg = tid & 7;
    const char* src = (const char*)(rpb + (size_t)(t0 + row) * C_);
    #pragma unroll
    for (int c = 0; c < 4; ++c) {
      u32x4 vv = *(const u32x4*)(src + seg * 64 + c * 16);
      *(u32x4*)(rp_l + (size_t)row * XP + seg * 64 + c * 16) = vv;
    }
  }
  __syncthreads();

  // ---- QR both heads: wave w owns n-tiles {2w, 2w+1}, all 4 m-tiles ----
  #pragma unroll
  for (int nn = 0; nn < 2; ++nn) {
    const int nt = 2 * w + nn;
    u32x4 bq0[8], bq1[8];
    #pragma unroll
    for (int kk = 0; kk < 8; ++kk) {
      bq0[kk] = *(const u32x4*)(qth0 + (size_t)(16 * nt + l15) * C_ +
                                32 * kk + 8 * lq);
      bq1[kk] = *(const u32x4*)(qth1 + (size_t)(16 * nt + l15) * C_ +
                                32 * kk + 8 * lq);
    }
    #pragma unroll
    for (int mm = 0; mm < 4; ++mm) {
      u32x4 am[8];
      #pragma unroll
      for (int kk = 0; kk < 8; ++kk)
        am[kk] = *(const u32x4*)(rp_l + (size_t)(16 * mm + l15) * XP +
                                 64 * kk + 16 * lq);
      f32x4 q0 = (f32x4)0.f, q1 = (f32x4)0.f;
      #pragma unroll
      for (int kk = 0; kk < 8; ++kk) {
        q0 = mfma16(am[kk], bq0[kk], q0);
        q1 = mfma16(am[kk], bq1[kk], q1);
      }
      #pragma unroll
      for (int rr = 0; rr < 4; ++rr) {
        size_t off = (size_t)(16 * mm + 4 * lq + rr) * XP + (16 * nt + l15) * 2;
        *(u16*)(x0 + off) = f2b(q0[rr]);
        *(u16*)(x1 + off) = f2b(q1[rr]);
      }
    }
  }
  __syncthreads();

  // ---- Z_full: wave w -> rows 32mh..+32, cols 64nq..+64; bg shared ----
  f32x4 a0[2][4], a1[2][4];
  #pragma unroll
  for (int m = 0; m < 2; ++m)
    #pragma unroll
    for (int n = 0; n < 4; ++n) { a0[m][n] = (f32x4)0.f; a1[m][n] = (f32x4)0.f; }

  #pragma unroll
  for (int n = 0; n < 4; ++n) {
    const int nt = 4 * nq + n;
    u32x4 bg[8];
    #pragma unroll
    for (int kk = 0; kk < 8; ++kk)
      bg[kk] = *(const u32x4*)(gt + (size_t)(16 * nt + l15) * C_ +
                               32 * kk + 8 * lq);
    #pragma unroll
    for (int m = 0; m < 2; ++m) {
      const size_t roff = (size_t)(16 * (2 * mh + m) + l15) * XP;
      u32x4 qa0[8], qa1[8];
      #pragma unroll
      for (int kk = 0; kk < 8; ++kk) {
        qa0[kk] = *(const u32x4*)(x0 + roff + 64 * kk + 16 * lq);
        qa1[kk] = *(const u32x4*)(x1 + roff + 64 * kk + 16 * lq);
      }
      #pragma unroll
      for (int kk = 0; kk < 8; ++kk) {
        a0[m][n] = mfma16(qa0[kk], bg[kk], a0[m][n]);
        a1[m][n] = mfma16(qa1[kk], bg[kk], a1[m][n]);
      }
    }
  }

  // ---- S: waves 0-3 head0 / 4-7 head1; wave does m-tile (w&3), 4 u-tiles ----
  {
    const int ms = w & 3;
    const char* xs = (w >> 2) ? x1 : x0;
    char* ss = (w >> 2) ? s1 : s0;
    u32x4 qa3[8];
    #pragma unroll
    for (int kk = 0; kk < 8; ++kk)
      qa3[kk] = *(const u32x4*)(xs + (size_t)(16 * ms + l15) * XP +
                                64 * kk + 16 * lq);
    #pragma unroll
    for (int un = 0; un < 4; ++un) {
      u32x4 bs[8];
      #pragma unroll
      for (int kk = 0; kk < 8; ++kk)
        bs[kk] = *(const u32x4*)(rp_l + (size_t)(16 * un + l15) * XP +
                                 64 * kk + 16 * lq);
      f32x4 sacc = (f32x4)0.f;
      #pragma unroll
      for (int kk = 0; kk < 8; ++kk) sacc = mfma16(qa3[kk], bs[kk], sacc);
      #pragma unroll
      for (int rr = 0; rr < 4; ++rr) {
        int tl = 16 * ms + 4 * lq + rr;
        int ul = 16 * un + l15;
        float sv = (ul > tl) ? 0.f : sacc[rr];
        *(u16*)(ss + (size_t)tl * SP + ul * 2) = f2b(sv);
      }
    }
  }
  __syncthreads();  // all x/rp_l reads done; s0/s1 visible

  // ---- Z_loc both heads: vb shared ----
  {
    u32x4 sa0[2][2], sa1[2][2];
    #pragma unroll
    for (int m = 0; m < 2; ++m)
      #pragma unroll
      for (int kk = 0; kk < 2; ++kk) {
        size_t off = (size_t)(16 * (2 * mh + m) + l15) * SP + 64 * kk + 16 * lq;
        sa0[m][kk] = *(const u32x4*)(s0 + off);
        sa1[m][kk] = *(const u32x4*)(s1 + off);
      }
    #pragma unroll
    for (int n = 0; n < 4; ++n) {
      const int nt = 4 * nq + n;
      #pragma unroll
      for (int kk = 0; kk < 2; ++kk) {
        u32x4 vb = *(const u32x4*)(rtb + (size_t)(16 * nt + l15) * T_ +
                                   t0 + 32 * kk + 8 * lq);
        #pragma unroll
        for (int m = 0; m < 2; ++m) {
          a0[m][n] = mfma16(sa0[m][kk], vb, a0[m][n]);
          a1[m][n] = mfma16(sa1[m][kk], vb, a1[m][n]);
        }
      }
    }
  }

  // ---- Z (bf16) -> x0/x1 (disjoint per wave); a0/a1 die here ----
  #pragma unroll
  for (int m = 0; m < 2; ++m)
    #pragma unroll
    for (int n = 0; n < 4; ++n)
      #pragma unroll
      for (int rr = 0; rr < 4; ++rr) {
        size_t off = (size_t)(16 * (2 * mh + m) + 4 * lq + rr) * XP +
                     (16 * (4 * nq + n) + l15) * 2;
        *(u16*)(x0 + off) = f2b(a0[m][n][rr]);
        *(u16*)(x1 + off) = f2b(a1[m][n][rr]);
      }
  __syncthreads();

  // ---- fused epilogue: oa = Z0*E0^T + Z1*E1^T; wave rows 32mh, cols 64nq ----
  {
    const u16* e0 = ec + (size_t)(2 * hg) * 256;      // col-slice of EC row
    const u16* e1 = ec + (size_t)(2 * hg + 1) * 256;
    f32x4 oa[2][4];
    #pragma unroll
    for (int m = 0; m < 2; ++m)
      #pragma unroll
      for (int n = 0; n < 4; ++n) oa[m][n] = (f32x4)0.f;

    #pragma unroll
    for (int m = 0; m < 2; ++m) {
      const size_t roff = (size_t)(16 * (2 * mh + m) + l15) * XP;
      u32x4 za0[8], za1[8];
      #pragma unroll
      for (int kk = 0; kk < 8; ++kk) {
        za0[kk] = *(const u32x4*)(x0 + roff + 64 * kk + 16 * lq);
        za1[kk] = *(const u32x4*)(x1 + roff + 64 * kk + 16 * lq);
      }
      #pragma unroll
      for (int n = 0; n < 4; ++n) {
        const int irow = 64 * nq + 16 * n + l15;
        u32x4 eb0[8], eb1[8];
        #pragma unroll
        for (int kk = 0; kk < 8; ++kk) {
          eb0[kk] = *(const u32x4*)(e0 + (size_t)irow * KC + 32 * kk + 8 * lq);
          eb1[kk] = *(const u32x4*)(e1 + (size_t)irow * KC + 32 * kk + 8 * lq);
        }
        #pragma unroll
        for (int kk = 0; kk < 8; ++kk) {
          oa[m][n] = mfma16(za0[kk], eb0[kk], oa[m][n]);
          oa[m][n] = mfma16(za1[kk], eb1[kk], oa[m][n]);
        }
      }
    }

    // plain stores to this head-pair's partial buffer (disjoint per wave)
    float* pb = part + ((size_t)(hg * B_ + b) * T_ + t0) * C_;
    #pragma unroll
    for (int m = 0; m < 2; ++m)
      #pragma unroll
      for (int n = 0; n < 4; ++n)
        #pragma unroll
        for (int rr = 0; rr < 4; ++rr)
          pb[(size_t)(32 * mh + 16 * m + 4 * lq + rr) * C_ +
             64 * nq + 16 * n + l15] = oa[m][n][rr];
  }
}

// ---- k_final: out = p0 + p1 + p2 + p3 (f32x4 vectorized) ----
__global__ __launch_bounds__(256) void k_final(const float* __restrict__ part,
                                               float* __restrict__ out) {
  const size_t idx = (size_t)blockIdx.x * 256 + threadIdx.x;
  const size_t N = (size_t)B_ * T_ * C_ / 4;
  const f32x4* p = (const f32x4*)part;
  f32x4 s = p[idx] + p[N + idx] + p[2 * N + idx] + p[3 * N + idx];
  ((f32x4*)out)[idx] = s;
}

extern "C" void kernel_launch(void* const* d_in, const int* in_sizes, int n_in,
                              void* d_out, int out_size, void* d_ws, size_t ws_size,
                              hipStream_t stream) {
  (void)ws_size; (void)out_size;
  const float* rp_f = nullptr;
  const float* sm[2] = {nullptr, nullptr};
  int ns = 0;
  for (int i = 0; i < n_in; ++i) {
    if (in_sizes[i] == 2097152) {
      rp_f = (const float*)d_in[i];
    } else if (ns < 2) {
      sm[ns++] = (const float*)d_in[i];
    }
  }
  const float* E_f = sm[0];
  const float* Q_f = sm[1];

  // ws (58 MB): G [0,16M) | rbf [16,20M) | rpT [20,24M) | Qt [24,25M)
  //             | EC [25,26M) | partials f32 [26,58M)  (4 x B x T x C)
  const size_t MB = 1024 * 1024;
  u16* G   = (u16*)d_ws;
  u16* rbf = (u16*)((char*)d_ws + 16 * MB);
  u16* rpT = (u16*)((char*)d_ws + 20 * MB);
  u16* qtb = (u16*)((char*)d_ws + 24 * MB);
  u16* ec  = (u16*)((char*)d_ws + 25 * MB);
  float* part = (float*)((char*)d_ws + 26 * MB);
  float* outf = (float*)d_out;

  k_prep<<<1152, 256, 0, stream>>>(rp_f, E_f, Q_f, rbf, rpT, qtb, ec);
  k_gram<<<dim3(16, 4, 4), 256, 0, stream>>>(rpT, G);
  k_z<<<dim3(32, 4, 4), 512, 0, stream>>>(rbf, rpT, qtb, G, ec, part);
  k_final<<<2048, 256, 0, stream>>>(part, outf);
}

// Round 24
// 119.156 us; speedup vs baseline: 1.4453x; 1.0085x over previous
//
#include <hip/hip_runtime.h>
#include <stdint.h>

typedef unsigned short u16;
typedef __attribute__((ext_vector_type(4))) float f32x4;
typedef __attribute__((ext_vector_type(4))) uint32_t u32x4;
typedef __attribute__((ext_vector_type(8))) __bf16 bf16x8;

#define B_ 4
#define H_ 8
#define T_ 2048
#define C_ 256
#define KC 2048  /* concatenated K = H*C (EC row length) */
#define NCH 32   /* 64-row G chunks per b */
#define XP 528   /* 256-col bf16 LDS pitch (bytes) */
#define SP 144   /* 64-col bf16 LDS pitch (bytes) */
#define OPW 260  /* f32 words per oa_l row (1040 B pitch) */

static __device__ __forceinline__ f32x4 mfma16(u32x4 a, u32x4 b, f32x4 c) {
  union { u32x4 u; bf16x8 b; } A, Bb;
  A.u = a; Bb.u = b;
  return __builtin_amdgcn_mfma_f32_16x16x32_bf16(A.b, Bb.b, c, 0, 0, 0);
}
static __device__ __forceinline__ u16 f2b(float f) {
  union { __bf16 h; u16 u; } r; r.h = (__bf16)f; return r.u;
}

// ---- k_prep: rp->bf16 + rp^T + Q^T + E->EC permute, one launch ----
__global__ __launch_bounds__(256) void k_prep(const float* __restrict__ rp_f,
                                              const float* __restrict__ E_f,
                                              const float* __restrict__ Q_f,
                                              u16* __restrict__ rbf,
                                              u16* __restrict__ rpT,
                                              u16* __restrict__ qtb,
                                              u16* __restrict__ ec) {
  __shared__ u16 l[64][72];
  const int r = blockIdx.x, tid = threadIdx.x;
  if (r < 512) {
    const int b = r >> 7, i0 = ((r >> 5) & 3) * 64, t0 = (r & 31) * 64;
    const int tj = tid & 63, tq = tid >> 6;
    const float* src = rp_f + (size_t)b * T_ * C_;
    u16* rb = rbf + (size_t)b * T_ * C_;
    #pragma unroll
    for (int rr = 0; rr < 16; ++rr) {
      int tl = rr * 4 + tq;
      u16 v = f2b(src[(size_t)(t0 + tl) * C_ + i0 + tj]);
      l[tl][tj] = v;
      rb[(size_t)(t0 + tl) * C_ + i0 + tj] = v;
    }
    __syncthreads();
    u16* dst = rpT + (size_t)b * C_ * T_;
    #pragma unroll
    for (int rr = 0; rr < 16; ++rr) {
      int il = rr * 4 + tq;
      dst[(size_t)(i0 + il) * T_ + t0 + tj] = l[tj][il];
    }
  } else if (r < 640) {
    const int q = r - 512;
    const int h = q >> 4, i0 = ((q >> 2) & 3) * 64, j0 = (q & 3) * 64;
    const int tj = tid & 63, tq = tid >> 6;
    const float* qh = Q_f + (size_t)h * C_ * C_;
    #pragma unroll
    for (int rr = 0; rr < 16; ++rr) {
      int i = rr * 4 + tq;
      l[i][tj] = f2b(qh[(size_t)(i0 + i) * C_ + j0 + tj]);
    }
    __syncthreads();
    u16* qth = qtb + (size_t)h * C_ * C_;
    #pragma unroll
    for (int rr = 0; rr < 16; ++rr) {
      int j = rr * 4 + tq;
      qth[(size_t)(j0 + j) * C_ + i0 + tj] = l[tj][j];
    }
  } else {  // E[h][i][j] -> EC[i][h*256+j] (bf16)
    const int q = r - 640;
    size_t e = ((size_t)q * 256 + tid) * 4;
    int h = (int)(e >> 16), i = (int)((e >> 8) & 255), j = (int)(e & 255);
    f32x4 v = *(const f32x4*)(E_f + e);
    union { u16 h4[4]; uint64_t qq; } p;
    #pragma unroll
    for (int c = 0; c < 4; ++c) p.h4[c] = f2b(v[c]);
    *(uint64_t*)(ec + (size_t)i * KC + h * 256 + j) = p.qq;
  }
}

// ---- k_gram: G_excl[b][k][i][j] = sum_{u<64k} rp[u][i]*rp[u][j], bf16 ----
__global__ __launch_bounds__(256) void k_gram(const u16* __restrict__ rpT,
                                              u16* __restrict__ G) {
  __shared__ u16 gls[4][16][20];
  const int js = blockIdx.x, iq = blockIdx.y, b = blockIdx.z;
  const int tid = threadIdx.x, lane = tid & 63, v = tid >> 6;
  const int l15 = lane & 15, lq = lane >> 4;
  const u16* rtb = rpT + (size_t)b * C_ * T_;
  const int irow = 64 * iq + 16 * v;
  const int rrow = lane >> 2, rc4 = (lane & 3) * 4;

  f32x4 acc = (f32x4)0.f;

  for (int k = 0; k < NCH; ++k) {
    #pragma unroll
    for (int rr = 0; rr < 4; ++rr)
      gls[v][4 * lq + rr][l15] = f2b(acc[rr]);
    __builtin_amdgcn_wave_barrier();
    u16* gk = G + (size_t)(b * NCH + k) * C_ * C_;
    *(uint64_t*)(gk + (size_t)(irow + rrow) * C_ + 16 * js + rc4) =
        *(const uint64_t*)&gls[v][rrow][rc4];
    __builtin_amdgcn_wave_barrier();

    u32x4 am[2], bn[2];
    #pragma unroll
    for (int kk = 0; kk < 2; ++kk) {
      am[kk] = *(const u32x4*)(rtb + (size_t)(irow + l15) * T_ +
                               64 * k + 32 * kk + 8 * lq);
      bn[kk] = *(const u32x4*)(rtb + (size_t)(16 * js + l15) * T_ +
                               64 * k + 32 * kk + 8 * lq);
    }
    #pragma unroll
    for (int kk = 0; kk < 2; ++kk)
      acc = mfma16(am[kk], bn[kk], acc);
  }
}

// ---- k_z: dual-head pass + fused epilogue (eb-hoisted, coalesced stores) ----
// part[hg][b][t][i] = Z_h0*E_h0^T + Z_h1*E_h1^T for h = {2hg, 2hg+1}.
__global__ __launch_bounds__(512, 2) void k_z(const u16* __restrict__ rbf,
                                              const u16* __restrict__ rpT,
                                              const u16* __restrict__ qtb,
                                              const u16* __restrict__ G,
                                              const u16* __restrict__ ec,
                                              float* __restrict__ part) {
  __shared__ __align__(16) char smem[119808];
  char* rp_l = smem;                 // [64][528]
  char* x0   = smem + 33792;         // QR/Z head0
  char* x1   = smem + 67584;         // QR/Z head1
  char* s0   = smem + 101376;        // S head0 [64][144]
  char* s1   = smem + 110592;        // S head1
  float* oa_l = (float*)(smem + 33792);  // epilogue f32 [64][260w], over x0/x1

  const int tile = blockIdx.x, b = blockIdx.y, hg = blockIdx.z;
  const int t0 = tile * 64;
  const int tid = threadIdx.x, lane = tid & 63, w = tid >> 6;
  const int l15 = lane & 15, lq = lane >> 4;
  const int mh = w >> 2, nq = w & 3;

  const u16* rpb = rbf + (size_t)b * T_ * C_;
  const u16* rtb = rpT + (size_t)b * C_ * T_;
  const u16* gt  = G + (size_t)(b * NCH + tile) * C_ * C_;
  const u16* qth0 = qtb + (size_t)(2 * hg) * C_ * C_;
  const u16* qth1 = qtb + (size_t)(2 * hg + 1) * C_ * C_;

  // ---- stage rp diagonal tile ----
  {
    const int row = tid >> 3, seg = tid & 7;
    const char* src = (const char*)(rpb + (size_t)(t0 + row) * C_);
    #pragma unroll
    for (int c = 0; c < 4; ++c) {
      u32x4 vv = *(const u32x4*)(src + seg * 64 + c * 16);
      *(u32x4*)(rp_l + (size_t)row * XP + seg * 64 + c * 16) = vv;
    }
  }
  __syncthreads();

  // ---- QR both heads: wave w owns n-tiles {2w, 2w+1}, all 4 m-tiles ----
  #pragma unroll
  for (int nn = 0; nn < 2; ++nn) {
    const int nt = 2 * w + nn;
    u32x4 bq0[8], bq1[8];
    #pragma unroll
    for (int kk = 0; kk < 8; ++kk) {
      bq0[kk] = *(const u32x4*)(qth0 + (size_t)(16 * nt + l15) * C_ +
                                32 * kk + 8 * lq);
      bq1[kk] = *(const u32x4*)(qth1 + (size_t)(16 * nt + l15) * C_ +
                                32 * kk + 8 * lq);
    }
    #pragma unroll
    for (int mm = 0; mm < 4; ++mm) {
      u32x4 am[8];
      #pragma unroll
      for (int kk = 0; kk < 8; ++kk)
        am[kk] = *(const u32x4*)(rp_l + (size_t)(16 * mm + l15) * XP +
                                 64 * kk + 16 * lq);
      f32x4 q0 = (f32x4)0.f, q1 = (f32x4)0.f;
      #pragma unroll
      for (int kk = 0; kk < 8; ++kk) {
        q0 = mfma16(am[kk], bq0[kk], q0);
        q1 = mfma16(am[kk], bq1[kk], q1);
      }
      #pragma unroll
      for (int rr = 0; rr < 4; ++rr) {
        size_t off = (size_t)(16 * mm + 4 * lq + rr) * XP + (16 * nt + l15) * 2;
        *(u16*)(x0 + off) = f2b(q0[rr]);
        *(u16*)(x1 + off) = f2b(q1[rr]);
      }
    }
  }
  __syncthreads();

  // ---- Z_full: wave w -> rows 32mh..+32, cols 64nq..+64; bg shared ----
  f32x4 a0[2][4], a1[2][4];
  #pragma unroll
  for (int m = 0; m < 2; ++m)
    #pragma unroll
    for (int n = 0; n < 4; ++n) { a0[m][n] = (f32x4)0.f; a1[m][n] = (f32x4)0.f; }

  #pragma unroll
  for (int n = 0; n < 4; ++n) {
    const int nt = 4 * nq + n;
    u32x4 bg[8];
    #pragma unroll
    for (int kk = 0; kk < 8; ++kk)
      bg[kk] = *(const u32x4*)(gt + (size_t)(16 * nt + l15) * C_ +
                               32 * kk + 8 * lq);
    #pragma unroll
    for (int m = 0; m < 2; ++m) {
      const size_t roff = (size_t)(16 * (2 * mh + m) + l15) * XP;
      u32x4 qa0[8], qa1[8];
      #pragma unroll
      for (int kk = 0; kk < 8; ++kk) {
        qa0[kk] = *(const u32x4*)(x0 + roff + 64 * kk + 16 * lq);
        qa1[kk] = *(const u32x4*)(x1 + roff + 64 * kk + 16 * lq);
      }
      #pragma unroll
      for (int kk = 0; kk < 8; ++kk) {
        a0[m][n] = mfma16(qa0[kk], bg[kk], a0[m][n]);
        a1[m][n] = mfma16(qa1[kk], bg[kk], a1[m][n]);
      }
    }
  }

  // ---- S: waves 0-3 head0 / 4-7 head1; wave does m-tile (w&3), 4 u-tiles ----
  {
    const int ms = w & 3;
    const char* xs = (w >> 2) ? x1 : x0;
    char* ss = (w >> 2) ? s1 : s0;
    u32x4 qa3[8];
    #pragma unroll
    for (int kk = 0; kk < 8; ++kk)
      qa3[kk] = *(const u32x4*)(xs + (size_t)(16 * ms + l15) * XP +
                                64 * kk + 16 * lq);
    #pragma unroll
    for (int un = 0; un < 4; ++un) {
      u32x4 bs[8];
      #pragma unroll
      for (int kk = 0; kk < 8; ++kk)
        bs[kk] = *(const u32x4*)(rp_l + (size_t)(16 * un + l15) * XP +
                                 64 * kk + 16 * lq);
      f32x4 sacc = (f32x4)0.f;
      #pragma unroll
      for (int kk = 0; kk < 8; ++kk) sacc = mfma16(qa3[kk], bs[kk], sacc);
      #pragma unroll
      for (int rr = 0; rr < 4; ++rr) {
        int tl = 16 * ms + 4 * lq + rr;
        int ul = 16 * un + l15;
        float sv = (ul > tl) ? 0.f : sacc[rr];
        *(u16*)(ss + (size_t)tl * SP + ul * 2) = f2b(sv);
      }
    }
  }
  __syncthreads();  // all x/rp_l reads done; s0/s1 visible

  // ---- Z_loc both heads: vb shared ----
  {
    u32x4 sa0[2][2], sa1[2][2];
    #pragma unroll
    for (int m = 0; m < 2; ++m)
      #pragma unroll
      for (int kk = 0; kk < 2; ++kk) {
        size_t off = (size_t)(16 * (2 * mh + m) + l15) * SP + 64 * kk + 16 * lq;
        sa0[m][kk] = *(const u32x4*)(s0 + off);
        sa1[m][kk] = *(const u32x4*)(s1 + off);
      }
    #pragma unroll
    for (int n = 0; n < 4; ++n) {
      const int nt = 4 * nq + n;
      #pragma unroll
      for (int kk = 0; kk < 2; ++kk) {
        u32x4 vb = *(const u32x4*)(rtb + (size_t)(16 * nt + l15) * T_ +
                                   t0 + 32 * kk + 8 * lq);
        #pragma unroll
        for (int m = 0; m < 2; ++m) {
          a0[m][n] = mfma16(sa0[m][kk], vb, a0[m][n]);
          a1[m][n] = mfma16(sa1[m][kk], vb, a1[m][n]);
        }
      }
    }
  }

  // ---- Z (bf16) -> x0/x1 (disjoint per wave); a0/a1 die here ----
  #pragma unroll
  for (int m = 0; m < 2; ++m)
    #pragma unroll
    for (int n = 0; n < 4; ++n)
      #pragma unroll
      for (int rr = 0; rr < 4; ++rr) {
        size_t off = (size_t)(16 * (2 * mh + m) + 4 * lq + rr) * XP +
                     (16 * (4 * nq + n) + l15) * 2;
        *(u16*)(x0 + off) = f2b(a0[m][n][rr]);
        *(u16*)(x1 + off) = f2b(a1[m][n][rr]);
      }
  __syncthreads();

  // ---- fused epilogue: oa = Z0*E0^T + Z1*E1^T; n-outer (eb loaded once) ----
  f32x4 oa[2][4];
  #pragma unroll
  for (int m = 0; m < 2; ++m)
    #pragma unroll
    for (int n = 0; n < 4; ++n) oa[m][n] = (f32x4)0.f;
  {
    const u16* e0 = ec + (size_t)(2 * hg) * 256;      // col-slice of EC row
    const u16* e1 = ec + (size_t)(2 * hg + 1) * 256;

    #pragma unroll
    for (int n = 0; n < 4; ++n) {
      const int irow = 64 * nq + 16 * n + l15;
      u32x4 eb0[8], eb1[8];
      #pragma unroll
      for (int kk = 0; kk < 8; ++kk) {
        eb0[kk] = *(const u32x4*)(e0 + (size_t)irow * KC + 32 * kk + 8 * lq);
        eb1[kk] = *(const u32x4*)(e1 + (size_t)irow * KC + 32 * kk + 8 * lq);
      }
      #pragma unroll
      for (int m = 0; m < 2; ++m) {
        const size_t roff = (size_t)(16 * (2 * mh + m) + l15) * XP;
        u32x4 za0[8], za1[8];
        #pragma unroll
        for (int kk = 0; kk < 8; ++kk) {
          za0[kk] = *(const u32x4*)(x0 + roff + 64 * kk + 16 * lq);
          za1[kk] = *(const u32x4*)(x1 + roff + 64 * kk + 16 * lq);
        }
        #pragma unroll
        for (int kk = 0; kk < 8; ++kk) {
          oa[m][n] = mfma16(za0[kk], eb0[kk], oa[m][n]);
          oa[m][n] = mfma16(za1[kk], eb1[kk], oa[m][n]);
        }
      }
    }
  }
  __syncthreads();  // all x0/x1 reads done; oa_l may overwrite the region

  // ---- oa -> f32 LDS (2-way max bank aliasing), then coalesced stores ----
  #pragma unroll
  for (int m = 0; m < 2; ++m)
    #pragma unroll
    for (int n = 0; n < 4; ++n)
      #pragma unroll
      for (int rr = 0; rr < 4; ++rr)
        oa_l[(size_t)(32 * mh + 16 * m + 4 * lq + rr) * OPW +
             64 * nq + 16 * n + l15] = oa[m][n][rr];
  __syncthreads();
  {
    const int row = tid >> 3, seg = tid & 7;
    const float* src = oa_l + (size_t)row * OPW + seg * 32;
    float* pb = part + ((size_t)(hg * B_ + b) * T_ + t0 + row) * C_ + seg * 32;
    #pragma unroll
    for (int c = 0; c < 8; ++c)
      *(f32x4*)(pb + c * 4) = *(const f32x4*)(src + c * 4);
  }
}

// ---- k_final: out = p0 + p1 + p2 + p3 (f32x4 vectorized) ----
__global__ __launch_bounds__(256) void k_final(const float* __restrict__ part,
                                               float* __restrict__ out) {
  const size_t idx = (size_t)blockIdx.x * 256 + threadIdx.x;
  const size_t N = (size_t)B_ * T_ * C_ / 4;
  const f32x4* p = (const f32x4*)part;
  f32x4 s = p[idx] + p[N + idx] + p[2 * N + idx] + p[3 * N + idx];
  ((f32x4*)out)[idx] = s;
}

extern "C" void kernel_launch(void* const* d_in, const int* in_sizes, int n_in,
                              void* d_out, int out_size, void* d_ws, size_t ws_size,
                              hipStream_t stream) {
  (void)ws_size; (void)out_size;
  const float* rp_f = nullptr;
  const float* sm[2] = {nullptr, nullptr};
  int ns = 0;
  for (int i = 0; i < n_in; ++i) {
    if (in_sizes[i] == 2097152) {
      rp_f = (const float*)d_in[i];
    } else if (ns < 2) {
      sm[ns++] = (const float*)d_in[i];
    }
  }
  const float* E_f = sm[0];
  const float* Q_f = sm[1];

  // ws (58 MB): G [0,16M) | rbf [16,20M) | rpT [20,24M) | Qt [24,25M)
  //             | EC [25,26M) | partials f32 [26,58M)  (4 x B x T x C)
  const size_t MB = 1024 * 1024;
  u16* G   = (u16*)d_ws;
  u16* rbf = (u16*)((char*)d_ws + 16 * MB);
  u16* rpT = (u16*)((char*)d_ws + 20 * MB);
  u16* qtb = (u16*)((char*)d_ws + 24 * MB);
  u16* ec  = (u16*)((char*)d_ws + 25 * MB);
  float* part = (float*)((char*)d_ws + 26 * MB);
  float* outf = (float*)d_out;

  k_prep<<<1152, 256, 0, stream>>>(rp_f, E_f, Q_f, rbf, rpT, qtb, ec);
  k_gram<<<dim3(16, 4, 4), 256, 0, stream>>>(rpT, G);
  k_z<<<dim3(32, 4, 4), 512, 0, stream>>>(rbf, rpT, qtb, G, ec, part);
  k_final<<<2048, 256, 0, stream>>>(part, outf);
}